// Round 3
// baseline (155.493 us; speedup 1.0000x reference)
//
#include <hip/hip_runtime.h>
#include <hip/hip_bf16.h>

#define T_SEQ   2048
#define BATCH   2
#define DMODEL  1024
#define NHEADS  16
#define HDIM    64
#define WINDOW  128

typedef __attribute__((ext_vector_type(8))) short bf16x8;
typedef __attribute__((ext_vector_type(4))) float f32x4;

// async global->LDS 16B per lane; LDS dest = wave-uniform base + lane*16
__device__ inline void gld_lds16(const __hip_bfloat16* g, __hip_bfloat16* l) {
    __builtin_amdgcn_global_load_lds(
        (const __attribute__((address_space(1))) unsigned int*)g,
        (__attribute__((address_space(3))) unsigned int*)l, 16, 0, 0);
}

// inline-asm LDS read: invisible to the compiler's waitcnt pass, so no
// auto-inserted vmcnt/lgkm drains. Manual counted waits own correctness.
__device__ inline bf16x8 ds_readb128(const __hip_bfloat16* p) {
    bf16x8 r;
    asm volatile("ds_read_b128 %0, %1"
                 : "=v"(r)
                 : "v"((const __attribute__((address_space(3))) __hip_bfloat16*)p));
    return r;
}

// fp32 -> bf16 bulk convert, exact 1D grid: lid<2048 -> x (4M elems),
// else 512 blocks per weight slot (1M each).
__global__ __launch_bounds__(256) void cvt_kernel(
    const float* __restrict__ x,  const float* __restrict__ Wq,
    const float* __restrict__ Wk, const float* __restrict__ Wv,
    const float* __restrict__ Wo,
    __hip_bfloat16* __restrict__ xb, __hip_bfloat16* __restrict__ Wb)
{
    const int lid = blockIdx.x;
    const float* src;
    __hip_bfloat16* dst;
    int blk;
    if (lid < 2048) { src = x; dst = xb; blk = lid; }
    else {
        int slot = (lid - 2048) >> 9;           // 0..3
        blk = (lid - 2048) & 511;
        src = (slot == 0) ? Wq : (slot == 1) ? Wk : (slot == 2) ? Wv : Wo;
        dst = Wb + (size_t)slot * 1024 * 1024;
    }
    int i = (blk * 256 + threadIdx.x) * 8;
    float4 a = *(const float4*)(src + i);
    float4 b = *(const float4*)(src + i + 4);
    __hip_bfloat16 pk[8] = {
        __float2bfloat16(a.x), __float2bfloat16(a.y),
        __float2bfloat16(a.z), __float2bfloat16(a.w),
        __float2bfloat16(b.x), __float2bfloat16(b.y),
        __float2bfloat16(b.z), __float2bfloat16(b.w)};
    *(uint4*)(dst + i) = *(uint4*)pk;
}

// ---------------------------------------------------------------------------
// QKV GEMM, 256x256 tile, counted-lgkm software pipeline (R3 restructure).
// C = A[4096,1024] * Wpacked[3072,1024]^T, fused z = n/1024 selects Q/K/V.
// 8 waves (2M x 4N), per-wave 128x64 output = acc[8][4] f32x4.
// LDS 128 KiB: 2 dbuf x (A 256x64 + B 256x64), 8-chunk rotation swizzle
// (row r slot s holds k-chunk (s-r)&7 -> read slot (kc+r)&7; 0 conflicts
// measured). Per K-tile: 24 b128 reads/wave (B held across mi-halves),
// 4 MFMA groups of 16, reads for group i+1 issued BEFORE group i's MFMAs,
// gated by counted lgkmcnt (in-order DS retirement). Barriers: 2/tile —
//   mid-tile (after own vmcnt(0)) publishes stage(t+1) before R0' reads it;
//   tile-end (after lgkm(0) drain) protects LDS from next stage's DMA.
// Hazard audit: stage(t+1)->buf pn issued at tile-t start; last cross-wave
// reads of pn were tile t-1's R1/R2/R3, all drained by t-1's lgkm(0)+barrier.
// R0'(next tile's kk0 frags) reads buf pn after the mid-tile barrier.
// ---------------------------------------------------------------------------
__device__ inline void stageA(const __hip_bfloat16* __restrict__ A,
                              __hip_bfloat16* dst, int m0, int k0, int half,
                              int w, int lane)
{
#pragma unroll
    for (int i = 0; i < 2; ++i) {
        int g0   = w * 16 + i * 8;
        int row0 = (g0 & 63) + ((g0 >> 6) << 7) + (half << 6);
        int r    = row0 + (lane >> 3);
        int gcx  = ((lane & 7) - r) & 7;
        gld_lds16(A + (size_t)(m0 + r) * DMODEL + k0 + gcx * 8, dst + row0 * 64);
    }
}

__device__ inline void stageB(const __hip_bfloat16* __restrict__ W,
                              __hip_bfloat16* dst, int n0, int k0, int half,
                              int w, int lane)
{
#pragma unroll
    for (int i = 0; i < 2; ++i) {
        int g0   = w * 16 + i * 8;
        int row0 = (g0 & 31) + ((g0 >> 5) << 6) + (half << 5);
        int r    = row0 + (lane >> 3);
        int gcx  = ((lane & 7) - r) & 7;
        gld_lds16(W + (size_t)(n0 + r) * DMODEL + k0 + gcx * 8, dst + row0 * 64);
    }
}

__device__ inline bf16x8 rdfrag(const __hip_bfloat16* buf, int r, int kc) {
    return ds_readb128(&buf[r * 64 + (((kc + r) & 7) << 3)]);
}

__global__ __launch_bounds__(512, 2) void gemm_qkv(
    const __hip_bfloat16* __restrict__ A,
    const __hip_bfloat16* __restrict__ Wp,   // packed [Wq;Wk;Wv] = [3072,1024]
    __hip_bfloat16* __restrict__ C0,
    __hip_bfloat16* __restrict__ C1,
    __hip_bfloat16* __restrict__ C2)
{
    // bijective XCD-chunked remap: 192 blocks, 24 contiguous per XCD
    const int lid   = blockIdx.x;
    const int wgid  = (lid & 7) * 24 + (lid >> 3);
    const int bn    = wgid % 12;
    const int bm    = wgid / 12;
    const int m0    = bm * 256;
    const int n0    = bn * 256;
    const int z     = n0 >> 10;          // 0=Q 1=K 2=V (256 | 1024 -> no straddle)
    const int cbase = n0 & 1023;

    __shared__ __hip_bfloat16 As[2][256 * 64];   // 64 KiB
    __shared__ __hip_bfloat16 Bs[2][256 * 64];   // 64 KiB

    const int t    = threadIdx.x;
    const int lane = t & 63;
    const int w    = t >> 6;       // wave 0..7
    const int wr   = w >> 2;       // 0..1  (M)
    const int wc   = w & 3;        // 0..3  (N)
    const int lrow = lane & 15;
    const int quad = lane >> 4;
    const int arow = wr * 128;     // wave A-row base in tile
    const int brow = wc * 64;      // wave B-row base in tile

    f32x4 acc[8][4];
#pragma unroll
    for (int i = 0; i < 8; ++i)
#pragma unroll
        for (int j = 0; j < 4; ++j)
            acc[i][j] = (f32x4){0.f, 0.f, 0.f, 0.f};

    // prologue: stage tile 0, publish, preload kk0 fragments (R0), drain
    stageA(A,  As[0], m0, 0, 0, w, lane);
    stageB(Wp, Bs[0], n0, 0, 0, w, lane);
    stageB(Wp, Bs[0], n0, 0, 1, w, lane);
    stageA(A,  As[0], m0, 0, 1, w, lane);
    asm volatile("s_waitcnt vmcnt(0)" ::: "memory");
    __builtin_amdgcn_s_barrier();

    bf16x8 aLa[4], aHa[4], aLb[4], aHb[4], bA[4], bB[4];

#pragma unroll
    for (int mi = 0; mi < 4; ++mi)
        aLa[mi] = rdfrag(As[0], arow + mi * 16 + lrow, quad);
#pragma unroll
    for (int ni = 0; ni < 4; ++ni)
        bA[ni] = rdfrag(Bs[0], brow + ni * 16 + lrow, quad);
    asm volatile("s_waitcnt lgkmcnt(0)" ::: "memory");
    __builtin_amdgcn_sched_barrier(0);

    for (int tt = 0; tt < 16; ++tt) {
        const int p  = tt & 1;
        const int pn = p ^ 1;
        const __hip_bfloat16* Ar = As[p];
        const __hip_bfloat16* Br = Bs[p];
        const bool pf = (tt < 15);
        const __hip_bfloat16* Arn = pf ? As[pn] : As[p];  // dummy re-read on last
        const __hip_bfloat16* Brn = pf ? Bs[pn] : Bs[p];
        const int k1 = pf ? ((tt + 1) << 6) : 0;

        // stage next tile (safe: tile-end barrier of t-1 drained all reads of pn)
        if (pf) {
            stageA(A,  As[pn], m0, k1, 0, w, lane);
            stageB(Wp, Bs[pn], n0, k1, 0, w, lane);
            stageB(Wp, Bs[pn], n0, k1, 1, w, lane);
            stageA(A,  As[pn], m0, k1, 1, w, lane);
        }
        // R1: A-miH @ kk0
#pragma unroll
        for (int mi = 0; mi < 4; ++mi)
            aHa[mi] = rdfrag(Ar, arow + (mi + 4) * 16 + lrow, quad);

        // G0: miL x all @ kk0  (aLa,bA drained before loop entry)
        __builtin_amdgcn_s_setprio(1);
#pragma unroll
        for (int mi = 0; mi < 4; ++mi)
#pragma unroll
            for (int ni = 0; ni < 4; ++ni)
                acc[mi][ni] = __builtin_amdgcn_mfma_f32_16x16x32_bf16(
                    aLa[mi], bA[ni], acc[mi][ni], 0, 0, 0);
        __builtin_amdgcn_s_setprio(0);

        // R2: A-miL @ kk1 + B-all @ kk1
#pragma unroll
        for (int mi = 0; mi < 4; ++mi)
            aLb[mi] = rdfrag(Ar, arow + mi * 16 + lrow, 4 + quad);
#pragma unroll
        for (int ni = 0; ni < 4; ++ni)
            bB[ni] = rdfrag(Br, brow + ni * 16 + lrow, 4 + quad);

        asm volatile("s_waitcnt lgkmcnt(8)" ::: "memory");  // R1 done, R2 in flight
        __builtin_amdgcn_sched_barrier(0);
        __builtin_amdgcn_s_setprio(1);
#pragma unroll
        for (int mi = 0; mi < 4; ++mi)                       // G1: miH x all @ kk0
#pragma unroll
            for (int ni = 0; ni < 4; ++ni)
                acc[mi + 4][ni] = __builtin_amdgcn_mfma_f32_16x16x32_bf16(
                    aHa[mi], bA[ni], acc[mi + 4][ni], 0, 0, 0);
        __builtin_amdgcn_s_setprio(0);

        // publish stage(t+1): own loads drained + barrier -> all waves' landed
        asm volatile("s_waitcnt vmcnt(0)" ::: "memory");
        __builtin_amdgcn_s_barrier();

        // R3: A-miH @ kk1
#pragma unroll
        for (int mi = 0; mi < 4; ++mi)
            aHb[mi] = rdfrag(Ar, arow + (mi + 4) * 16 + lrow, 4 + quad);

        asm volatile("s_waitcnt lgkmcnt(4)" ::: "memory");  // R2 done, R3 in flight
        __builtin_amdgcn_sched_barrier(0);
        __builtin_amdgcn_s_setprio(1);
#pragma unroll
        for (int mi = 0; mi < 4; ++mi)                       // G2: miL x all @ kk1
#pragma unroll
            for (int ni = 0; ni < 4; ++ni)
                acc[mi][ni] = __builtin_amdgcn_mfma_f32_16x16x32_bf16(
                    aLb[mi], bB[ni], acc[mi][ni], 0, 0, 0);
        __builtin_amdgcn_s_setprio(0);

        // R0': next tile's kk0 fragments (buf pn, published at mid-tile barrier)
#pragma unroll
        for (int mi = 0; mi < 4; ++mi)
            aLa[mi] = rdfrag(Arn, arow + mi * 16 + lrow, quad);
#pragma unroll
        for (int ni = 0; ni < 4; ++ni)
            bA[ni] = rdfrag(Brn, brow + ni * 16 + lrow, quad);

        asm volatile("s_waitcnt lgkmcnt(8)" ::: "memory");  // R3 done, R0' in flight
        __builtin_amdgcn_sched_barrier(0);
        __builtin_amdgcn_s_setprio(1);
#pragma unroll
        for (int mi = 0; mi < 4; ++mi)                       // G3: miH x all @ kk1
#pragma unroll
            for (int ni = 0; ni < 4; ++ni)
                acc[mi + 4][ni] = __builtin_amdgcn_mfma_f32_16x16x32_bf16(
                    aHb[mi], bB[ni], acc[mi + 4][ni], 0, 0, 0);
        __builtin_amdgcn_s_setprio(0);

        asm volatile("s_waitcnt lgkmcnt(0)" ::: "memory");  // R0' drained
        __builtin_amdgcn_s_barrier();                        // tile end
    }

    // per-head l2norm for Q,K (wave cols = exactly one 64-wide head)
    if (z != 2) {
#pragma unroll
        for (int mi = 0; mi < 8; ++mi) {
#pragma unroll
            for (int rr = 0; rr < 4; ++rr) {
                float ss = 0.f;
#pragma unroll
                for (int ni = 0; ni < 4; ++ni)
                    ss += acc[mi][ni][rr] * acc[mi][ni][rr];
                ss += __shfl_xor(ss, 1);
                ss += __shfl_xor(ss, 2);
                ss += __shfl_xor(ss, 4);
                ss += __shfl_xor(ss, 8);
                float inv = 1.0f / fmaxf(sqrtf(ss), 1e-6f);
#pragma unroll
                for (int ni = 0; ni < 4; ++ni)
                    acc[mi][ni][rr] *= inv;
            }
        }
    }

    __hip_bfloat16* C = (z == 0) ? C0 : (z == 1) ? C1 : C2;
    // C/D layout col=lane&15, row=quad*4+reg  [verified m89/m91]
#pragma unroll
    for (int mi = 0; mi < 8; ++mi) {
#pragma unroll
        for (int rr = 0; rr < 4; ++rr) {
            int row = m0 + arow + mi * 16 + quad * 4 + rr;
            __hip_bfloat16* Crow = C + (size_t)row * DMODEL + cbase + brow + lrow;
#pragma unroll
            for (int ni = 0; ni < 4; ++ni)
                Crow[ni * 16] = __float2bfloat16(acc[mi][ni][rr]);
        }
    }
}

// O-projection GEMM: 64x128 tile, 4 waves, fp32 C, BK=64 (LDS 24 KB),
// same rotation swizzle + XCD cluster decode.
__global__ __launch_bounds__(256) void gemm_o(
    const __hip_bfloat16* __restrict__ A,
    const __hip_bfloat16* __restrict__ W,
    float* __restrict__ C,
    int M, int N, int K)
{
    const int lid   = blockIdx.x + 8 * blockIdx.y;
    const int xcd   = lid & 7;
    const int s     = lid >> 3;
    const int m_loc = s & 15;
    const int n_loc = s >> 4;

    const int m0 = ((xcd & 3) * 16 + m_loc) * 64;
    const int n0 = ((xcd >> 2) * 4 + n_loc) * 128;

    __shared__ __hip_bfloat16 As[64 * 64];
    __shared__ __hip_bfloat16 Bs[128 * 64];

    const int t    = threadIdx.x;
    const int lane = t & 63;
    const int wv   = t >> 6;

    const int drow = lane >> 3;
    const int sl   = lane & 7;

    const int wm   = (wv >> 1) * 32;
    const int wn   = (wv & 1) * 64;
    const int lrow = lane & 15;
    const int quad = lane >> 4;

    f32x4 acc[2][4];
#pragma unroll
    for (int i = 0; i < 2; i++)
#pragma unroll
        for (int j = 0; j < 4; j++)
            acc[i][j] = (f32x4){0.f, 0.f, 0.f, 0.f};

    for (int k0 = 0; k0 < K; k0 += 64) {
#pragma unroll
        for (int inst = 0; inst < 2; inst++) {
            int r0 = wv * 16 + inst * 8;
            int r  = r0 + drow;
            int gcx = (sl - r) & 7;
            gld_lds16(A + (size_t)(m0 + r) * K + k0 + gcx * 8, &As[r0 * 64]);
        }
#pragma unroll
        for (int inst = 0; inst < 4; inst++) {
            int r0 = wv * 32 + inst * 8;
            int r  = r0 + drow;
            int gcx = (sl - r) & 7;
            gld_lds16(W + (size_t)(n0 + r) * K + k0 + gcx * 8, &Bs[r0 * 64]);
        }
        __syncthreads();

#pragma unroll
        for (int kk = 0; kk < 2; kk++) {
            bf16x8 af[2], bfv[4];
#pragma unroll
            for (int mi = 0; mi < 2; mi++) {
                int r = wm + mi * 16 + lrow;
                af[mi] = *(const bf16x8*)&As[r * 64 + ((kk * 4 + quad + r) & 7) * 8];
            }
#pragma unroll
            for (int ni = 0; ni < 4; ni++) {
                int r = wn + ni * 16 + lrow;
                bfv[ni] = *(const bf16x8*)&Bs[r * 64 + ((kk * 4 + quad + r) & 7) * 8];
            }
#pragma unroll
            for (int mi = 0; mi < 2; mi++)
#pragma unroll
                for (int ni = 0; ni < 4; ni++)
                    acc[mi][ni] = __builtin_amdgcn_mfma_f32_16x16x32_bf16(
                        af[mi], bfv[ni], acc[mi][ni], 0, 0, 0);
        }
        __syncthreads();
    }

#pragma unroll
    for (int mi = 0; mi < 2; mi++) {
#pragma unroll
        for (int rr = 0; rr < 4; rr++) {
            int row = m0 + wm + mi * 16 + quad * 4 + rr;
            float* Crow = C + (size_t)row * N + n0 + wn + lrow;
#pragma unroll
            for (int ni = 0; ni < 4; ni++)
                Crow[ni * 16] = acc[mi][ni][rr];
        }
    }
}

// MFMA sliding-window attention, 128-query blocks (8 waves, 512 thr).
// Grid 512 = exactly 2 blocks/CU, one balanced round. LDS 75 KB:
// KsP union (Ks 256x64 phase 1 / P 8x16x168 phase 2) + Vt 64x264.
__global__ __launch_bounds__(512) void attn_kernel(
    const __hip_bfloat16* __restrict__ Q,
    const __hip_bfloat16* __restrict__ K,
    const __hip_bfloat16* __restrict__ V,
    __hip_bfloat16* __restrict__ O)
{
    const int qb = blockIdx.x * 128;
    const int h  = blockIdx.y;
    const int b  = blockIdx.z;

    __shared__ __hip_bfloat16 KsP[8 * 16 * 168];  // >= 256*64; P overlay later
    __shared__ __hip_bfloat16 Vt[64 * 264];       // V^T, swizzled key blocks

    const size_t base = ((size_t)b * T_SEQ) * DMODEL + h * HDIM;
    const int t    = threadIdx.x;
    const int lane = t & 63;
    const int w    = t >> 6;                      // wave 0..7

    // K staging via DMA: wave w covers rows [w*32, w*32+32), 4 insts of 8 rows.
    {
        const int drow = lane >> 3, sl = lane & 7;
#pragma unroll
        for (int inst = 0; inst < 4; inst++) {
            int r0 = w * 32 + inst * 8;
            int r  = r0 + drow;
            int gcx = (sl - r) & 7;
            int j  = min(qb + r, T_SEQ - 1);
            gld_lds16(K + base + (size_t)j * DMODEL + gcx * 8, &KsP[r0 * 64]);
        }
    }
    // V staging: 256 tasks (dim-chunk c, key-block b0), 8x8 register transpose,
    // swizzled b128 writes: sg = (b0&~7)|((b0+c)&7).
    if (t < 256) {
        int c  = t & 7;
        int b0 = t >> 3;              // 0..31
        int sg = (b0 & ~7) | ((b0 + c) & 7);
        unsigned short m[8][8];
#pragma unroll
        for (int i = 0; i < 8; i++) {
            int j = min(qb + b0 * 8 + i, T_SEQ - 1);
            uint4 u = *(const uint4*)(V + base + (size_t)j * DMODEL + c * 8);
            unsigned short tmp[8];
            *(uint4*)tmp = u;
#pragma unroll
            for (int e = 0; e < 8; e++) m[e][i] = tmp[e];
        }
#pragma unroll
        for (int e = 0; e < 8; e++)
            *(uint4*)&Vt[(c * 8 + e) * 264 + sg * 8] = *(uint4*)m[e];
    }
    // zero tail slot 32 (keys >= 256; P is zero there but data must be finite)
    if (t < 64) {
        uint4 zz = {0, 0, 0, 0};
        *(uint4*)&Vt[t * 264 + 256] = zz;
    }
    __syncthreads();

    const int col  = lane & 15;
    const int quad = lane >> 4;
    const float slope = exp2f(-8.0f * (float)h / 15.0f);

    const __hip_bfloat16* qp = Q + base + (size_t)(qb + w * 16 + col) * DMODEL + quad * 8;
    bf16x8 qf0 = *(const bf16x8*)(qp);
    bf16x8 qf1 = *(const bf16x8*)(qp + 32);

    f32x4 sc[9];
#pragma unroll
    for (int kt = 0; kt < 9; kt++) {
        sc[kt] = (f32x4){0.f, 0.f, 0.f, 0.f};
        int r = w * 16 + kt * 16 + col;
        bf16x8 kb0 = *(const bf16x8*)&KsP[r * 64 + ((quad     + r) & 7) * 8];
        bf16x8 kb1 = *(const bf16x8*)&KsP[r * 64 + ((quad + 4 + r) & 7) * 8];
        sc[kt] = __builtin_amdgcn_mfma_f32_16x16x32_bf16(qf0, kb0, sc[kt], 0, 0, 0);
        sc[kt] = __builtin_amdgcn_mfma_f32_16x16x32_bf16(qf1, kb1, sc[kt], 0, 0, 0);
    }

    float mx[4] = {-3e38f, -3e38f, -3e38f, -3e38f};
#pragma unroll
    for (int kt = 0; kt < 9; kt++) {
#pragma unroll
        for (int r = 0; r < 4; r++) {
            int ql  = quad * 4 + r;
            int rel = kt * 16 + col - ql;
            int ka  = qb + w * 16 + kt * 16 + col;
            bool valid = (rel >= 0) && (rel < WINDOW) && (ka < T_SEQ);
            float v = valid ? (sc[kt][r] - (float)rel * slope) : -1e30f;
            sc[kt][r] = v;
            mx[r] = fmaxf(mx[r], v);
        }
    }
#pragma unroll
    for (int r = 0; r < 4; r++) {
        mx[r] = fmaxf(mx[r], __shfl_xor(mx[r], 1));
        mx[r] = fmaxf(mx[r], __shfl_xor(mx[r], 2));
        mx[r] = fmaxf(mx[r], __shfl_xor(mx[r], 4));
        mx[r] = fmaxf(mx[r], __shfl_xor(mx[r], 8));
    }
    float sm[4] = {0.f, 0.f, 0.f, 0.f};
#pragma unroll
    for (int kt = 0; kt < 9; kt++) {
#pragma unroll
        for (int r = 0; r < 4; r++) {
            float e = __expf(sc[kt][r] - mx[r]);
            sc[kt][r] = e;
            sm[r] += e;
        }
    }
#pragma unroll
    for (int r = 0; r < 4; r++) {
        sm[r] += __shfl_xor(sm[r], 1);
        sm[r] += __shfl_xor(sm[r], 2);
        sm[r] += __shfl_xor(sm[r], 4);
        sm[r] += __shfl_xor(sm[r], 8);
        sm[r] = 1.0f / sm[r];
    }

    // all Ks reads done -> overlay P (per-wave region, stride 168)
    __syncthreads();
    __hip_bfloat16* Ps = KsP + w * (16 * 168);
#pragma unroll
    for (int kt = 0; kt < 9; kt++)
#pragma unroll
        for (int r = 0; r < 4; r++)
            Ps[(quad * 4 + r) * 168 + kt * 16 + col] = __float2bfloat16(sc[kt][r] * sm[r]);
#pragma unroll
    for (int i = 0; i < 4; i++)
        Ps[(lane & 15) * 168 + 144 + quad * 4 + i] = __float2bfloat16(0.f);
    __syncthreads();

    // PV: A = P[q][key], B = Vt[dim][key] (swizzled slots)
    f32x4 o[4];
#pragma unroll
    for (int nd = 0; nd < 4; nd++) o[nd] = (f32x4){0.f, 0.f, 0.f, 0.f};
#pragma unroll
    for (int kc = 0; kc < 5; kc++) {
        bf16x8 pf = *(const bf16x8*)&Ps[col * 168 + kc * 32 + quad * 8];
        int bblk = w * 2 + kc * 4 + quad;
#pragma unroll
        for (int nd = 0; nd < 4; nd++) {
            int d  = nd * 16 + col;
            int sg = (bblk < 32) ? ((bblk & ~7) | ((bblk + (d >> 3)) & 7)) : 32;
            bf16x8 vf = *(const bf16x8*)&Vt[d * 264 + sg * 8];
            o[nd] = __builtin_amdgcn_mfma_f32_16x16x32_bf16(pf, vf, o[nd], 0, 0, 0);
        }
    }

#pragma unroll
    for (int r = 0; r < 4; r++) {
        __hip_bfloat16* op = O + base + (size_t)(qb + w * 16 + quad * 4 + r) * DMODEL + col;
#pragma unroll
        for (int nd = 0; nd < 4; nd++)
            op[nd * 16] = __float2bfloat16(o[nd][r]);
    }
}

extern "C" void kernel_launch(void* const* d_in, const int* in_sizes, int n_in,
                              void* d_out, int out_size, void* d_ws, size_t ws_size,
                              hipStream_t stream)
{
    const float* x  = (const float*)d_in[0];
    const float* Wq = (const float*)d_in[1];
    const float* Wk = (const float*)d_in[2];
    const float* Wv = (const float*)d_in[3];
    const float* Wo = (const float*)d_in[4];
    float* out = (float*)d_out;

    const size_t MT = (size_t)BATCH * T_SEQ;          // 4096 rows
    __hip_bfloat16* Qw = (__hip_bfloat16*)d_ws;       // 8 MB each (bf16)
    __hip_bfloat16* Kw = Qw + MT * DMODEL;
    __hip_bfloat16* Vw = Kw + MT * DMODEL;
    __hip_bfloat16* XA = Vw + MT * DMODEL;            // xb (pre-attn) / AO (post-attn)
    __hip_bfloat16* Wb = XA + MT * DMODEL;            // 4 x 1M bf16 weights

    cvt_kernel<<<4096, 256, 0, stream>>>(x, Wq, Wk, Wv, Wo, XA, Wb);

    // fused QKV: packed weight rows [Wq;Wk;Wv] = 3072 x 1024, 16x12 = 192 blocks
    gemm_qkv<<<dim3(192), 512, 0, stream>>>(XA, Wb, Qw, Kw, Vw);

    dim3 g2(T_SEQ / 128, NHEADS, BATCH);
    attn_kernel<<<g2, 512, 0, stream>>>(Qw, Kw, Vw, XA);

    dim3 g3(DMODEL / 128, MT / 64, 1);
    gemm_o<<<g3, 256, 0, stream>>>(
        XA, Wb + 3 * 1024 * 1024, out, (int)MT, DMODEL, DMODEL);
}

// Round 4
// 148.541 us; speedup vs baseline: 1.0468x; 1.0468x over previous
//
#include <hip/hip_runtime.h>
#include <hip/hip_bf16.h>

#define T_SEQ   2048
#define BATCH   2
#define DMODEL  1024
#define NHEADS  16
#define HDIM    64
#define WINDOW  128

typedef __attribute__((ext_vector_type(8))) short bf16x8;
typedef __attribute__((ext_vector_type(4))) float f32x4;

#define LGKM(n)  asm volatile("s_waitcnt lgkmcnt(" #n ")" ::: "memory")
#define VMCNT(n) asm volatile("s_waitcnt vmcnt(" #n ")" ::: "memory")
#define SCHEDB() __builtin_amdgcn_sched_barrier(0)
#define BAR()    __builtin_amdgcn_s_barrier()

// async global->LDS 16B per lane; LDS dest = wave-uniform base + lane*16
__device__ inline void gld_lds16(const __hip_bfloat16* g, __hip_bfloat16* l) {
    __builtin_amdgcn_global_load_lds(
        (const __attribute__((address_space(1))) unsigned int*)g,
        (__attribute__((address_space(3))) unsigned int*)l, 16, 0, 0);
}

// inline-asm LDS read: invisible to the compiler's waitcnt pass (no auto
// vmcnt(0)/lgkm(0) drains). Manual counted waits own correctness.
__device__ inline bf16x8 ds_readb128(const __hip_bfloat16* p) {
    bf16x8 r;
    asm volatile("ds_read_b128 %0, %1"
                 : "=v"(r)
                 : "v"((const __attribute__((address_space(3))) __hip_bfloat16*)p));
    return r;
}

// fp32 -> bf16 bulk convert, exact 1D grid: lid<2048 -> x (4M elems),
// else 512 blocks per weight slot (1M each).
__global__ __launch_bounds__(256) void cvt_kernel(
    const float* __restrict__ x,  const float* __restrict__ Wq,
    const float* __restrict__ Wk, const float* __restrict__ Wv,
    const float* __restrict__ Wo,
    __hip_bfloat16* __restrict__ xb, __hip_bfloat16* __restrict__ Wb)
{
    const int lid = blockIdx.x;
    const float* src;
    __hip_bfloat16* dst;
    int blk;
    if (lid < 2048) { src = x; dst = xb; blk = lid; }
    else {
        int slot = (lid - 2048) >> 9;           // 0..3
        blk = (lid - 2048) & 511;
        src = (slot == 0) ? Wq : (slot == 1) ? Wk : (slot == 2) ? Wv : Wo;
        dst = Wb + (size_t)slot * 1024 * 1024;
    }
    int i = (blk * 256 + threadIdx.x) * 8;
    float4 a = *(const float4*)(src + i);
    float4 b = *(const float4*)(src + i + 4);
    __hip_bfloat16 pk[8] = {
        __float2bfloat16(a.x), __float2bfloat16(a.y),
        __float2bfloat16(a.z), __float2bfloat16(a.w),
        __float2bfloat16(b.x), __float2bfloat16(b.y),
        __float2bfloat16(b.z), __float2bfloat16(b.w)};
    *(uint4*)(dst + i) = *(uint4*)pk;
}

// ---------------------------------------------------------------------------
// QKV GEMM, 256x256 tile, half-K(32) rotation pipeline, NEVER-drain vmcnt.
// C = A[4096,1024]*Wp[3072,1024]^T; z = n0>>10 selects Q/K/V (256|1024).
// 8 waves (2Mx4N), wave out 128x64, acc[8][4] f32x4 (AGPRs).
// LDS: 4 slots x (A 256x32 + B 256x32) bf16 = 4 x 32KB = 128KB.
// Rows are 64B = 4 chunks of 16B; rotation swizzle: slot chunk s at row r
// holds k-chunk (s-r)&3; frag read chunk = (quad+r)&3 (bank-balanced: 8
// touches per 16B slot-group per b128 wave read — minimum).
// Schedule per phase h (32 phases, h = K/32 index):
//   stage(h+3)                 [4 gld -> slot (h+3)&3 = (h-1)&3]
//   lgkm(4)  -> B(h),A_L(h) retired (A_H(h) may be in flight)
//   MFMA miL(h) x16
//   reads B(h+1)x4, A_L(h+1)x4 [slot (h+1)&3; landed: prev boundary vmcnt(4)]
//   lgkm(8)  -> A_H(h) retired (8 newer outstanding)
//   MFMA miH(h) x16
//   reads A_H(h+1)x4
//   vmcnt(4) -> stage(h+1) landed (only stage(h+2)'s 4 may remain in flight)
//   s_barrier
// Hazards: stage(h+3) overwrites slot(h-1); every wave's reads of slot(h-1)
// retired before its lgkm gates in phase h-1, hence before barrier(h-1),
// hence before any wave's phase-h stage.  Reads(h+1) need all waves'
// stage(h+1) landed: each wave's vmcnt(4) at end of h-1 + barrier. DS ops
// retire in order (counted lgkm valid). Tail: phases 30/31 peeled (31 uses
// lgkm(0) mid-gate since no newer reads pad the count).
// ---------------------------------------------------------------------------
__global__ __launch_bounds__(512, 2) void gemm_qkv(
    const __hip_bfloat16* __restrict__ A,
    const __hip_bfloat16* __restrict__ Wp,   // packed [Wq;Wk;Wv] = [3072,1024]
    __hip_bfloat16* __restrict__ C0,
    __hip_bfloat16* __restrict__ C1,
    __hip_bfloat16* __restrict__ C2)
{
    // bijective XCD-chunked remap: 192 blocks, 24 contiguous per XCD
    const int lid   = blockIdx.x;
    const int wgid  = (lid & 7) * 24 + (lid >> 3);
    const int bn    = wgid % 12;
    const int bm    = wgid / 12;
    const int m0    = bm * 256;
    const int n0    = bn * 256;
    const int z     = n0 >> 10;
    const int cbase = n0 & 1023;

    __shared__ __hip_bfloat16 S[4][2][256 * 32];   // [slot][A/B][row*32+k]

    const int t    = threadIdx.x;
    const int lane = t & 63;
    const int w    = t >> 6;       // wave 0..7
    const int wr   = w >> 2;       // 0..1  (M)
    const int wc   = w & 3;        // 0..3  (N)
    const int lrow = lane & 15;
    const int quad = lane >> 4;
    const int arow = wr * 128;
    const int brow = wc * 64;

    f32x4 acc[8][4];
#pragma unroll
    for (int i = 0; i < 8; ++i)
#pragma unroll
        for (int j = 0; j < 4; ++j)
            acc[i][j] = (f32x4){0.f, 0.f, 0.f, 0.f};

    // stage phase h: A-half + B-half, 2 gld insts each (16 rows/wave/inst)
    auto STAGE = [&](int h) {
        const int slot = h & 3;
        const int k0   = h * 32;
        const int r    = (lane >> 2);
        const int c    = lane & 3;
#pragma unroll
        for (int i = 0; i < 2; ++i) {
            int row0 = i * 128 + w * 16;
            int row  = row0 + r;
            int gcx  = (c - row) & 3;
            gld_lds16(A + (size_t)(m0 + row) * DMODEL + k0 + gcx * 8,
                      &S[slot][0][row0 * 32]);
        }
#pragma unroll
        for (int i = 0; i < 2; ++i) {
            int row0 = i * 128 + w * 16;
            int row  = row0 + r;
            int gcx  = (c - row) & 3;
            gld_lds16(Wp + (size_t)(n0 + row) * DMODEL + k0 + gcx * 8,
                      &S[slot][1][row0 * 32]);
        }
    };

    auto RD = [&](const __hip_bfloat16* base, int r) -> bf16x8 {
        return ds_readb128(base + r * 32 + (((quad + r) & 3) << 3));
    };

    bf16x8 bf_[2][4], al_[2][4], ah_[2][4];

#define READS_BL(P, H) { \
    const __hip_bfloat16* Sb = &S[(H) & 3][1][0]; \
    const __hip_bfloat16* Sa = &S[(H) & 3][0][0]; \
    _Pragma("unroll") for (int ni = 0; ni < 4; ++ni) \
        bf_[P][ni] = RD(Sb, brow + ni * 16 + lrow); \
    _Pragma("unroll") for (int mi = 0; mi < 4; ++mi) \
        al_[P][mi] = RD(Sa, arow + mi * 16 + lrow); }

#define READS_AH(P, H) { \
    const __hip_bfloat16* Sa = &S[(H) & 3][0][0]; \
    _Pragma("unroll") for (int mi = 0; mi < 4; ++mi) \
        ah_[P][mi] = RD(Sa, arow + 64 + mi * 16 + lrow); }

#define MFMA_L(P) { \
    _Pragma("unroll") for (int mi = 0; mi < 4; ++mi) \
    _Pragma("unroll") for (int ni = 0; ni < 4; ++ni) \
        acc[mi][ni] = __builtin_amdgcn_mfma_f32_16x16x32_bf16( \
            al_[P][mi], bf_[P][ni], acc[mi][ni], 0, 0, 0); }

#define MFMA_H(P) { \
    _Pragma("unroll") for (int mi = 0; mi < 4; ++mi) \
    _Pragma("unroll") for (int ni = 0; ni < 4; ++ni) \
        acc[mi + 4][ni] = __builtin_amdgcn_mfma_f32_16x16x32_bf16( \
            ah_[P][mi], bf_[P][ni], acc[mi + 4][ni], 0, 0, 0); }

#define QBODY(H, P, PN, DO_STAGE, DO_READS, MIDGATE) { \
    if (DO_STAGE) STAGE((H) + 3); \
    LGKM(4); SCHEDB(); \
    __builtin_amdgcn_s_setprio(1); MFMA_L(P); __builtin_amdgcn_s_setprio(0); \
    if (DO_READS) READS_BL(PN, (H) + 1); \
    MIDGATE; SCHEDB(); \
    __builtin_amdgcn_s_setprio(1); MFMA_H(P); __builtin_amdgcn_s_setprio(0); \
    if (DO_READS) READS_AH(PN, (H) + 1); \
    VMCNT(4); BAR(); }

    // prologue: stage slots 0,1,2; land 0,1; pre-read phase 0 fragments
    STAGE(0); STAGE(1); STAGE(2);
    VMCNT(4);
    BAR();
    READS_BL(0, 0);
    READS_AH(0, 0);

    for (int it = 0; it < 15; ++it) {
        const int h = it * 2;
        QBODY(h,     0, 1, true,        true, LGKM(8));
        QBODY(h + 1, 1, 0, (it < 14),   true, LGKM(8));
    }
    QBODY(30, 0, 1, false, true,  LGKM(8));
    QBODY(31, 1, 0, false, false, LGKM(0));

#undef QBODY
#undef MFMA_H
#undef MFMA_L
#undef READS_AH
#undef READS_BL

    // per-head l2norm for Q,K (wave cols = exactly one 64-wide head)
    if (z != 2) {
#pragma unroll
        for (int mi = 0; mi < 8; ++mi) {
#pragma unroll
            for (int rr = 0; rr < 4; ++rr) {
                float ss = 0.f;
#pragma unroll
                for (int ni = 0; ni < 4; ++ni)
                    ss += acc[mi][ni][rr] * acc[mi][ni][rr];
                ss += __shfl_xor(ss, 1);
                ss += __shfl_xor(ss, 2);
                ss += __shfl_xor(ss, 4);
                ss += __shfl_xor(ss, 8);
                float inv = 1.0f / fmaxf(sqrtf(ss), 1e-6f);
#pragma unroll
                for (int ni = 0; ni < 4; ++ni)
                    acc[mi][ni][rr] *= inv;
            }
        }
    }

    __hip_bfloat16* C = (z == 0) ? C0 : (z == 1) ? C1 : C2;
    // C/D layout col=lane&15, row=quad*4+reg  [verified m89/m91]
#pragma unroll
    for (int mi = 0; mi < 8; ++mi) {
#pragma unroll
        for (int rr = 0; rr < 4; ++rr) {
            int row = m0 + arow + mi * 16 + quad * 4 + rr;
            __hip_bfloat16* Crow = C + (size_t)row * DMODEL + cbase + brow + lrow;
#pragma unroll
            for (int ni = 0; ni < 4; ++ni)
                Crow[ni * 16] = __float2bfloat16(acc[mi][ni][rr]);
        }
    }
}

// ---------------------------------------------------------------------------
// O-projection GEMM: 128x128 tile, 4 waves (2x2, wave out 64x64), same
// half-K(32)/4-slot never-drain pipeline. Grid 32x8 = 256 blocks = 100% CU
// fill (the old 64x128 kernel's structure was the round-3 fat). LDS 64KB.
// Per phase: 8 reads (A4+B4) for h+1 issued before the lgkm(8) gate for h.
// ---------------------------------------------------------------------------
__global__ __launch_bounds__(256, 2) void gemm_o(
    const __hip_bfloat16* __restrict__ A,
    const __hip_bfloat16* __restrict__ W,
    float* __restrict__ C)
{
    const int lid  = blockIdx.x;
    const int wgid = (lid & 7) * 32 + (lid >> 3);   // 256 blocks, 32/XCD
    const int bn   = wgid & 7;
    const int bm   = wgid >> 3;
    const int m0   = bm * 128;
    const int n0   = bn * 128;

    __shared__ __hip_bfloat16 S[4][2][128 * 32];    // 64 KiB

    const int t    = threadIdx.x;
    const int lane = t & 63;
    const int wv   = t >> 6;       // 0..3
    const int lrow = lane & 15;
    const int quad = lane >> 4;
    const int wm   = (wv >> 1) * 64;
    const int wn   = (wv & 1) * 64;

    f32x4 acc[4][4];
#pragma unroll
    for (int i = 0; i < 4; ++i)
#pragma unroll
        for (int j = 0; j < 4; ++j)
            acc[i][j] = (f32x4){0.f, 0.f, 0.f, 0.f};

    auto STAGE = [&](int h) {
        const int slot = h & 3;
        const int k0   = h * 32;
        const int r    = (lane >> 2);
        const int c    = lane & 3;
#pragma unroll
        for (int i = 0; i < 2; ++i) {
            int row0 = i * 64 + wv * 16;
            int row  = row0 + r;
            int gcx  = (c - row) & 3;
            gld_lds16(A + (size_t)(m0 + row) * DMODEL + k0 + gcx * 8,
                      &S[slot][0][row0 * 32]);
        }
#pragma unroll
        for (int i = 0; i < 2; ++i) {
            int row0 = i * 64 + wv * 16;
            int row  = row0 + r;
            int gcx  = (c - row) & 3;
            gld_lds16(W + (size_t)(n0 + row) * DMODEL + k0 + gcx * 8,
                      &S[slot][1][row0 * 32]);
        }
    };

    auto RD = [&](const __hip_bfloat16* base, int r) -> bf16x8 {
        return ds_readb128(base + r * 32 + (((quad + r) & 3) << 3));
    };

    bf16x8 a_[2][4], b_[2][4];

#define READS_O(P, H) { \
    const __hip_bfloat16* Sa = &S[(H) & 3][0][0]; \
    const __hip_bfloat16* Sb = &S[(H) & 3][1][0]; \
    _Pragma("unroll") for (int mi = 0; mi < 4; ++mi) \
        a_[P][mi] = RD(Sa, wm + mi * 16 + lrow); \
    _Pragma("unroll") for (int ni = 0; ni < 4; ++ni) \
        b_[P][ni] = RD(Sb, wn + ni * 16 + lrow); }

#define OBODY(H, P, PN, DO_STAGE, DO_READS, GATE) { \
    if (DO_STAGE) STAGE((H) + 3); \
    if (DO_READS) READS_O(PN, (H) + 1); \
    GATE; SCHEDB(); \
    __builtin_amdgcn_s_setprio(1); \
    _Pragma("unroll") for (int mi = 0; mi < 4; ++mi) \
    _Pragma("unroll") for (int ni = 0; ni < 4; ++ni) \
        acc[mi][ni] = __builtin_amdgcn_mfma_f32_16x16x32_bf16( \
            a_[P][mi], b_[P][ni], acc[mi][ni], 0, 0, 0); \
    __builtin_amdgcn_s_setprio(0); \
    VMCNT(4); BAR(); }

    STAGE(0); STAGE(1); STAGE(2);
    VMCNT(4);
    BAR();
    READS_O(0, 0);

    for (int it = 0; it < 15; ++it) {
        const int h = it * 2;
        OBODY(h,     0, 1, true,      true, LGKM(8));
        OBODY(h + 1, 1, 0, (it < 14), true, LGKM(8));
    }
    OBODY(30, 0, 1, false, true,  LGKM(8));
    OBODY(31, 1, 0, false, false, LGKM(0));

#undef OBODY
#undef READS_O

#pragma unroll
    for (int mi = 0; mi < 4; ++mi) {
#pragma unroll
        for (int rr = 0; rr < 4; ++rr) {
            int row = m0 + wm + mi * 16 + quad * 4 + rr;
            float* Crow = C + (size_t)row * DMODEL + n0 + wn + lrow;
#pragma unroll
            for (int ni = 0; ni < 4; ++ni)
                Crow[ni * 16] = acc[mi][ni][rr];
        }
    }
}

// MFMA sliding-window attention, 128-query blocks (8 waves, 512 thr).
// Grid 512 = exactly 2 blocks/CU, one balanced round. LDS 75 KB:
// KsP union (Ks 256x64 phase 1 / P 8x16x168 phase 2) + Vt 64x264.
__global__ __launch_bounds__(512) void attn_kernel(
    const __hip_bfloat16* __restrict__ Q,
    const __hip_bfloat16* __restrict__ K,
    const __hip_bfloat16* __restrict__ V,
    __hip_bfloat16* __restrict__ O)
{
    const int qb = blockIdx.x * 128;
    const int h  = blockIdx.y;
    const int b  = blockIdx.z;

    __shared__ __hip_bfloat16 KsP[8 * 16 * 168];  // >= 256*64; P overlay later
    __shared__ __hip_bfloat16 Vt[64 * 264];       // V^T, swizzled key blocks

    const size_t base = ((size_t)b * T_SEQ) * DMODEL + h * HDIM;
    const int t    = threadIdx.x;
    const int lane = t & 63;
    const int w    = t >> 6;                      // wave 0..7

    // K staging via DMA: wave w covers rows [w*32, w*32+32), 4 insts of 8 rows.
    {
        const int drow = lane >> 3, sl = lane & 7;
#pragma unroll
        for (int inst = 0; inst < 4; inst++) {
            int r0 = w * 32 + inst * 8;
            int r  = r0 + drow;
            int gcx = (sl - r) & 7;
            int j  = min(qb + r, T_SEQ - 1);
            gld_lds16(K + base + (size_t)j * DMODEL + gcx * 8, &KsP[r0 * 64]);
        }
    }
    // V staging: 256 tasks (dim-chunk c, key-block b0), 8x8 register transpose,
    // swizzled b128 writes: sg = (b0&~7)|((b0+c)&7).
    if (t < 256) {
        int c  = t & 7;
        int b0 = t >> 3;              // 0..31
        int sg = (b0 & ~7) | ((b0 + c) & 7);
        unsigned short m[8][8];
#pragma unroll
        for (int i = 0; i < 8; i++) {
            int j = min(qb + b0 * 8 + i, T_SEQ - 1);
            uint4 u = *(const uint4*)(V + base + (size_t)j * DMODEL + c * 8);
            unsigned short tmp[8];
            *(uint4*)tmp = u;
#pragma unroll
            for (int e = 0; e < 8; e++) m[e][i] = tmp[e];
        }
#pragma unroll
        for (int e = 0; e < 8; e++)
            *(uint4*)&Vt[(c * 8 + e) * 264 + sg * 8] = *(uint4*)m[e];
    }
    // zero tail slot 32 (keys >= 256; P is zero there but data must be finite)
    if (t < 64) {
        uint4 zz = {0, 0, 0, 0};
        *(uint4*)&Vt[t * 264 + 256] = zz;
    }
    __syncthreads();

    const int col  = lane & 15;
    const int quad = lane >> 4;
    const float slope = exp2f(-8.0f * (float)h / 15.0f);

    const __hip_bfloat16* qp = Q + base + (size_t)(qb + w * 16 + col) * DMODEL + quad * 8;
    bf16x8 qf0 = *(const bf16x8*)(qp);
    bf16x8 qf1 = *(const bf16x8*)(qp + 32);

    f32x4 sc[9];
#pragma unroll
    for (int kt = 0; kt < 9; kt++) {
        sc[kt] = (f32x4){0.f, 0.f, 0.f, 0.f};
        int r = w * 16 + kt * 16 + col;
        bf16x8 kb0 = *(const bf16x8*)&KsP[r * 64 + ((quad     + r) & 7) * 8];
        bf16x8 kb1 = *(const bf16x8*)&KsP[r * 64 + ((quad + 4 + r) & 7) * 8];
        sc[kt] = __builtin_amdgcn_mfma_f32_16x16x32_bf16(qf0, kb0, sc[kt], 0, 0, 0);
        sc[kt] = __builtin_amdgcn_mfma_f32_16x16x32_bf16(qf1, kb1, sc[kt], 0, 0, 0);
    }

    float mx[4] = {-3e38f, -3e38f, -3e38f, -3e38f};
#pragma unroll
    for (int kt = 0; kt < 9; kt++) {
#pragma unroll
        for (int r = 0; r < 4; r++) {
            int ql  = quad * 4 + r;
            int rel = kt * 16 + col - ql;
            int ka  = qb + w * 16 + kt * 16 + col;
            bool valid = (rel >= 0) && (rel < WINDOW) && (ka < T_SEQ);
            float v = valid ? (sc[kt][r] - (float)rel * slope) : -1e30f;
            sc[kt][r] = v;
            mx[r] = fmaxf(mx[r], v);
        }
    }
#pragma unroll
    for (int r = 0; r < 4; r++) {
        mx[r] = fmaxf(mx[r], __shfl_xor(mx[r], 1));
        mx[r] = fmaxf(mx[r], __shfl_xor(mx[r], 2));
        mx[r] = fmaxf(mx[r], __shfl_xor(mx[r], 4));
        mx[r] = fmaxf(mx[r], __shfl_xor(mx[r], 8));
    }
    float sm[4] = {0.f, 0.f, 0.f, 0.f};
#pragma unroll
    for (int kt = 0; kt < 9; kt++) {
#pragma unroll
        for (int r = 0; r < 4; r++) {
            float e = __expf(sc[kt][r] - mx[r]);
            sc[kt][r] = e;
            sm[r] += e;
        }
    }
#pragma unroll
    for (int r = 0; r < 4; r++) {
        sm[r] += __shfl_xor(sm[r], 1);
        sm[r] += __shfl_xor(sm[r], 2);
        sm[r] += __shfl_xor(sm[r], 4);
        sm[r] += __shfl_xor(sm[r], 8);
        sm[r] = 1.0f / sm[r];
    }

    // all Ks reads done -> overlay P (per-wave region, stride 168)
    __syncthreads();
    __hip_bfloat16* Ps = KsP + w * (16 * 168);
#pragma unroll
    for (int kt = 0; kt < 9; kt++)
#pragma unroll
        for (int r = 0; r < 4; r++)
            Ps[(quad * 4 + r) * 168 + kt * 16 + col] = __float2bfloat16(sc[kt][r] * sm[r]);
#pragma unroll
    for (int i = 0; i < 4; i++)
        Ps[(lane & 15) * 168 + 144 + quad * 4 + i] = __float2bfloat16(0.f);
    __syncthreads();

    // PV: A = P[q][key], B = Vt[dim][key] (swizzled slots)
    f32x4 o[4];
#pragma unroll
    for (int nd = 0; nd < 4; nd++) o[nd] = (f32x4){0.f, 0.f, 0.f, 0.f};
#pragma unroll
    for (int kc = 0; kc < 5; kc++) {
        bf16x8 pf = *(const bf16x8*)&Ps[col * 168 + kc * 32 + quad * 8];
        int bblk = w * 2 + kc * 4 + quad;
#pragma unroll
        for (int nd = 0; nd < 4; nd++) {
            int d  = nd * 16 + col;
            int sg = (bblk < 32) ? ((bblk & ~7) | ((bblk + (d >> 3)) & 7)) : 32;
            bf16x8 vf = *(const bf16x8*)&Vt[d * 264 + sg * 8];
            o[nd] = __builtin_amdgcn_mfma_f32_16x16x32_bf16(pf, vf, o[nd], 0, 0, 0);
        }
    }

#pragma unroll
    for (int r = 0; r < 4; r++) {
        __hip_bfloat16* op = O + base + (size_t)(qb + w * 16 + quad * 4 + r) * DMODEL + col;
#pragma unroll
        for (int nd = 0; nd < 4; nd++)
            op[nd * 16] = __float2bfloat16(o[nd][r]);
    }
}

extern "C" void kernel_launch(void* const* d_in, const int* in_sizes, int n_in,
                              void* d_out, int out_size, void* d_ws, size_t ws_size,
                              hipStream_t stream)
{
    const float* x  = (const float*)d_in[0];
    const float* Wq = (const float*)d_in[1];
    const float* Wk = (const float*)d_in[2];
    const float* Wv = (const float*)d_in[3];
    const float* Wo = (const float*)d_in[4];
    float* out = (float*)d_out;

    const size_t MT = (size_t)BATCH * T_SEQ;          // 4096 rows
    __hip_bfloat16* Qw = (__hip_bfloat16*)d_ws;       // 8 MB each (bf16)
    __hip_bfloat16* Kw = Qw + MT * DMODEL;
    __hip_bfloat16* Vw = Kw + MT * DMODEL;
    __hip_bfloat16* XA = Vw + MT * DMODEL;            // xb (pre-attn) / AO (post-attn)
    __hip_bfloat16* Wb = XA + MT * DMODEL;            // 4 x 1M bf16 weights

    cvt_kernel<<<4096, 256, 0, stream>>>(x, Wq, Wk, Wv, Wo, XA, Wb);

    // fused QKV: packed weight rows [Wq;Wk;Wv] = 3072 x 1024, 16x12 = 192 blocks
    gemm_qkv<<<dim3(192), 512, 0, stream>>>(XA, Wb, Qw, Kw, Vw);

    dim3 g2(T_SEQ / 128, NHEADS, BATCH);
    attn_kernel<<<g2, 512, 0, stream>>>(Qw, Kw, Vw, XA);

    gemm_o<<<dim3(256), 256, 0, stream>>>(XA, Wb + 3 * 1024 * 1024, out);
}